// Round 8
// baseline (378.033 us; speedup 1.0000x reference)
//
#include <hip/hip_runtime.h>
#include <hip/hip_bf16.h>

typedef float ff4 __attribute__((ext_vector_type(4)));
typedef short s8v __attribute__((ext_vector_type(8)));
typedef unsigned int u4v __attribute__((ext_vector_type(4)));

#define Hd 1024
#define Nn 256
#define KC 32
#define NCHUNK 32
#define RB 32

__device__ __forceinline__ unsigned bf16r(float f) {
    unsigned u = __builtin_bit_cast(unsigned, f);
    return (u + 0x7FFFu + ((u >> 16) & 1u)) >> 16;   // RNE f32->bf16
}

__device__ __forceinline__ unsigned cvtpk(float lo, float hi) {
    unsigned r;
    asm("v_cvt_pk_bf16_f32 %0, %1, %2" : "=v"(r) : "v"(lo), "v"(hi));
    return r;
}

// ---- memB chunk-major LINEAR: memB[c*8192 + r*32 + col] = bf16(mem[r][c*32+col])
// -> a wave's 8-frag read per (c,nt) is contiguous 1024 B (16-line transactions)
__global__ void conv_mem_kernel(const float* __restrict__ mem, unsigned short* __restrict__ memB) {
    int g = blockIdx.x * 256 + threadIdx.x;   // 0..32767
    int b = g & 3;
    int r = (g >> 2) & 255;
    int c = g >> 10;
    const float* src = mem + (size_t)r * Hd + c * KC + b * 8;
    ff4 a0 = *(const ff4*)src;
    ff4 a1 = *(const ff4*)(src + 4);
    u4v v;
    v[0] = bf16r(a0[0]) | (bf16r(a0[1]) << 16);
    v[1] = bf16r(a0[2]) | (bf16r(a0[3]) << 16);
    v[2] = bf16r(a1[0]) | (bf16r(a1[1]) << 16);
    v[3] = bf16r(a1[2]) | (bf16r(a1[3]) << 16);
    *(u4v*)(memB + (size_t)c * 8192 + (size_t)r * 32 + b * 8) = v;
}

// ---- Wbf[c][h] = bf16(Wout[h][c]), c in {0,1} ----
__global__ void conv_w_kernel(const float* __restrict__ Wout, unsigned short* __restrict__ Wbf) {
    int t = threadIdx.x;
    int c = t >> 7;
    int h0 = (t & 127) * 8;
    u4v v;
#pragma unroll
    for (int j = 0; j < 4; ++j) {
        unsigned lo = bf16r(Wout[(h0 + 2 * j) * 2 + c]);
        unsigned hi = bf16r(Wout[(h0 + 2 * j + 1) * 2 + c]);
        v[j] = lo | (hi << 16);
    }
    *(u4v*)(Wbf + (size_t)c * Hd + h0) = v;
}

// ---- Gram G = mem @ mem^T, stored chunk-major: Gcm[ (gj>>5)*8192 + gi*32 + (gj&31) ] ----
__global__ __launch_bounds__(256) void gram_kernel(const float* __restrict__ mem,
                                                   unsigned short* __restrict__ Gcm) {
    __shared__ float LA[32][132];
    __shared__ float LB[32][132];
    const int t = threadIdx.x;
    const int bi = blockIdx.x >> 3, bj = blockIdx.x & 7;
    const int j = t & 31, i0 = t >> 5;
    float acc0 = 0.f, acc1 = 0.f, acc2 = 0.f, acc3 = 0.f;
    for (int kc = 0; kc < Hd; kc += 128) {
        __syncthreads();
#pragma unroll
        for (int q = 0; q < 4; ++q) {
            int c = t + q * 256;
            int r = c >> 5, fc = (c & 31) << 2;
            *(ff4*)&LA[r][fc] = *(const ff4*)(mem + (size_t)(bi * 32 + r) * Hd + kc + fc);
            *(ff4*)&LB[r][fc] = *(const ff4*)(mem + (size_t)(bj * 32 + r) * Hd + kc + fc);
        }
        __syncthreads();
#pragma unroll 4
        for (int kk = 0; kk < 128; kk += 4) {
            ff4 b = *(const ff4*)&LB[j][kk];
            ff4 a0 = *(const ff4*)&LA[i0][kk];
            ff4 a1 = *(const ff4*)&LA[i0 + 8][kk];
            ff4 a2 = *(const ff4*)&LA[i0 + 16][kk];
            ff4 a3 = *(const ff4*)&LA[i0 + 24][kk];
            acc0 += a0[0]*b[0] + a0[1]*b[1] + a0[2]*b[2] + a0[3]*b[3];
            acc1 += a1[0]*b[0] + a1[1]*b[1] + a1[2]*b[2] + a1[3]*b[3];
            acc2 += a2[0]*b[0] + a2[1]*b[1] + a2[2]*b[2] + a2[3]*b[3];
            acc3 += a3[0]*b[0] + a3[1]*b[1] + a3[2]*b[2] + a3[3]*b[3];
        }
    }
    // G row gi, col gj -> chunk (gj>>5)=bj, within (gj&31)=j
    const size_t base = (size_t)bj * 8192 + (size_t)j;
    Gcm[base + (size_t)(bi * 32 + i0 +  0) * 32] = (unsigned short)bf16r(acc0);
    Gcm[base + (size_t)(bi * 32 + i0 +  8) * 32] = (unsigned short)bf16r(acc1);
    Gcm[base + (size_t)(bi * 32 + i0 + 16) * 32] = (unsigned short)bf16r(acc2);
    Gcm[base + (size_t)(bi * 32 + i0 + 24) * 32] = (unsigned short)bf16r(acc3);
}

// ---- fused main kernel: 32 rows/block, 4 waves (2 row-groups x 2 N-halves),
//      NO barriers / NO LDS in the main loop: B-frags streamed from L2 (contiguous),
//      u/m from HBM per-lane with register prefetch. Epilogue = R7's (proven). ----
__global__ __launch_bounds__(256, 3) void fused_kernel(
    const float* __restrict__ user, const float* __restrict__ music,
    const float* __restrict__ bout, const int* __restrict__ label,
    const unsigned short* __restrict__ memB,   // [32][256][32] bf16 chunk-major linear
    const unsigned short* __restrict__ Wbf,    // [2][1024] bf16
    const unsigned short* __restrict__ Gcm,    // [8][256][32] bf16 chunk-major
    float* __restrict__ out, float* __restrict__ partials)
{
    __shared__ __align__(16) unsigned short sAttn[32 * 264];   // 16896 B
    __shared__ float fMax[64], fSum[64], fCross[64], fQuad[64], fAux[32];

    const int t = threadIdx.x;
    const int w = t >> 6;
    const int l = t & 63;
    const int la = l & 15, lb = l >> 4;
    const int g = w >> 1;        // row-group (16 rows)
    const int h = w & 1;         // N-half (128 cols)
    const int row0 = blockIdx.x * RB;
    const int myrow = row0 + g * 16 + la;

    const float* uR = user  + (size_t)myrow * Hd + lb * 8;
    const float* mR = music + (size_t)myrow * Hd + lb * 8;
    const unsigned short* fbase = memB + h * 4096 + la * 32 + lb * 8;   // + k*8192 + nt*512
    const unsigned short* wrowB = Wbf + (size_t)(la < 2 ? la : 1) * Hd + lb * 8;
    const unsigned short* gbase = Gcm + h * 4096 + la * 32 + lb * 8;    // + ks*8192 + nt*512

    ff4 accL[8], accD[8];
#pragma unroll
    for (int i = 0; i < 8; ++i) { accL[i] = (ff4)0.0f; accD[i] = (ff4)0.0f; }
    ff4 accH = (ff4)0.0f;
    float sd2 = 0.f;

#define STEP(K, UA, UB, MA, MB)                                                 \
    {                                                                           \
        float s0 = UA[0]*MA[0], s1 = UA[1]*MA[1], s2 = UA[2]*MA[2], s3 = UA[3]*MA[3]; \
        float s4 = UB[0]*MB[0], s5 = UB[1]*MB[1], s6 = UB[2]*MB[2], s7 = UB[3]*MB[3]; \
        float d0 = UA[0]-MA[0], d1 = UA[1]-MA[1], d2 = UA[2]-MA[2], d3 = UA[3]-MA[3]; \
        float d4 = UB[0]-MB[0], d5 = UB[1]-MB[1], d6 = UB[2]-MB[2], d7 = UB[3]-MB[3]; \
        sd2 = fmaf(d0,d0,sd2); sd2 = fmaf(d1,d1,sd2); sd2 = fmaf(d2,d2,sd2); sd2 = fmaf(d3,d3,sd2); \
        sd2 = fmaf(d4,d4,sd2); sd2 = fmaf(d5,d5,sd2); sd2 = fmaf(d6,d6,sd2); sd2 = fmaf(d7,d7,sd2); \
        u4v ps, pd;                                                             \
        ps[0] = cvtpk(s0,s1); ps[1] = cvtpk(s2,s3); ps[2] = cvtpk(s4,s5); ps[3] = cvtpk(s6,s7); \
        pd[0] = cvtpk(d0,d1); pd[1] = cvtpk(d2,d3); pd[2] = cvtpk(d4,d5); pd[3] = cvtpk(d6,d7); \
        s8v fs = __builtin_bit_cast(s8v, ps);                                   \
        s8v fd = __builtin_bit_cast(s8v, pd);                                   \
        const unsigned short* fp = fbase + (size_t)(K) * 8192;                  \
        s8v bM[8];                                                              \
        _Pragma("unroll")                                                       \
        for (int nt = 0; nt < 8; ++nt) bM[nt] = *(const s8v*)(fp + nt * 512);   \
        _Pragma("unroll")                                                       \
        for (int nt = 0; nt < 8; ++nt) {                                        \
            accL[nt] = __builtin_amdgcn_mfma_f32_16x16x32_bf16(fs, bM[nt], accL[nt], 0, 0, 0); \
            accD[nt] = __builtin_amdgcn_mfma_f32_16x16x32_bf16(fd, bM[nt], accD[nt], 0, 0, 0); \
        }                                                                       \
        if (h == 0) {                                                           \
            s8v bW = *(const s8v*)(wrowB + (K) * KC);                           \
            accH = __builtin_amdgcn_mfma_f32_16x16x32_bf16(fs, bW, accH, 0, 0, 0); \
        }                                                                       \
    }

    // ---- register-prefetched, barrier-free K loop ----
    ff4 ua0 = *(const ff4*)(uR);
    ff4 ub0 = *(const ff4*)(uR + 4);
    ff4 ma0 = *(const ff4*)(mR);
    ff4 mb0 = *(const ff4*)(mR + 4);
    for (int k = 0; k < NCHUNK; k += 2) {
        ff4 ua1 = *(const ff4*)(uR + (k + 1) * KC);
        ff4 ub1 = *(const ff4*)(uR + (k + 1) * KC + 4);
        ff4 ma1 = *(const ff4*)(mR + (k + 1) * KC);
        ff4 mb1 = *(const ff4*)(mR + (k + 1) * KC + 4);
        STEP(k, ua0, ub0, ma0, mb0)
        if (k + 2 < NCHUNK) {
            ua0 = *(const ff4*)(uR + (k + 2) * KC);
            ub0 = *(const ff4*)(uR + (k + 2) * KC + 4);
            ma0 = *(const ff4*)(mR + (k + 2) * KC);
            mb0 = *(const ff4*)(mR + (k + 2) * KC + 4);
        }
        STEP(k + 1, ua1, ub1, ma1, mb1)
    }
#undef STEP

    // ---- classification head (cols 0,1 live in lanes la<2; h==0 waves only) ----
    if (h == 0 && la < 2) {
#pragma unroll
        for (int j = 0; j < 4; ++j) {
            int gr = row0 + g * 16 + lb * 4 + j;
            out[1 + gr * 2 + la] = accH[j] + bout[la];
        }
    }
    // ---- ||d||^2 per row: reduce over 4 lb col-groups; h==0 writes ----
    sd2 += __shfl_xor(sd2, 16);
    sd2 += __shfl_xor(sd2, 32);
    if (h == 0 && lb == 0) fAux[g * 16 + la] = sd2;

    // ---- half-softmax: local max & sumexp over this wave's 128 cols ----
    ff4 mx = accL[0];
#pragma unroll
    for (int nt = 1; nt < 8; ++nt) {
        mx[0] = fmaxf(mx[0], accL[nt][0]); mx[1] = fmaxf(mx[1], accL[nt][1]);
        mx[2] = fmaxf(mx[2], accL[nt][2]); mx[3] = fmaxf(mx[3], accL[nt][3]);
    }
#pragma unroll
    for (int s = 1; s < 16; s <<= 1) {
        mx[0] = fmaxf(mx[0], __shfl_xor(mx[0], s));
        mx[1] = fmaxf(mx[1], __shfl_xor(mx[1], s));
        mx[2] = fmaxf(mx[2], __shfl_xor(mx[2], s));
        mx[3] = fmaxf(mx[3], __shfl_xor(mx[3], s));
    }
    ff4 sm = (ff4)0.0f;
#pragma unroll
    for (int nt = 0; nt < 8; ++nt) {
        sm[0] += __expf(accL[nt][0] - mx[0]); sm[1] += __expf(accL[nt][1] - mx[1]);
        sm[2] += __expf(accL[nt][2] - mx[2]); sm[3] += __expf(accL[nt][3] - mx[3]);
    }
#pragma unroll
    for (int s = 1; s < 16; s <<= 1) {
        sm[0] += __shfl_xor(sm[0], s); sm[1] += __shfl_xor(sm[1], s);
        sm[2] += __shfl_xor(sm[2], s); sm[3] += __shfl_xor(sm[3], s);
    }
    if (la < 4) {
        const int grow = g * 16 + lb * 4 + la;
        float mv = (la == 0) ? mx[0] : (la == 1) ? mx[1] : (la == 2) ? mx[2] : mx[3];
        float sv = (la == 0) ? sm[0] : (la == 1) ? sm[1] : (la == 2) ? sm[2] : sm[3];
        fMax[h * 32 + grow] = mv;
        fSum[h * 32 + grow] = sv;
    }
    __syncthreads();

    // ---- combine halves -> per-row M, 1/denom ----
    ff4 Mr, Dinv;
#pragma unroll
    for (int j = 0; j < 4; ++j) {
        const int grow = g * 16 + lb * 4 + j;
        float m0 = fMax[grow], m1 = fMax[32 + grow];
        float M = fmaxf(m0, m1);
        float den = fSum[grow] * __expf(m0 - M) + fSum[32 + grow] * __expf(m1 - M);
        Mr[j] = M; Dinv[j] = 1.0f / den;
    }
    // ---- attn + cross partial ----
    ff4 cross = (ff4)0.0f;
#pragma unroll
    for (int nt = 0; nt < 8; ++nt) {
        accL[nt][0] = __expf(accL[nt][0] - Mr[0]) * Dinv[0];
        accL[nt][1] = __expf(accL[nt][1] - Mr[1]) * Dinv[1];
        accL[nt][2] = __expf(accL[nt][2] - Mr[2]) * Dinv[2];
        accL[nt][3] = __expf(accL[nt][3] - Mr[3]) * Dinv[3];
        cross[0] = fmaf(accL[nt][0], accD[nt][0], cross[0]);
        cross[1] = fmaf(accL[nt][1], accD[nt][1], cross[1]);
        cross[2] = fmaf(accL[nt][2], accD[nt][2], cross[2]);
        cross[3] = fmaf(accL[nt][3], accD[nt][3], cross[3]);
    }
#pragma unroll
    for (int s = 1; s < 16; s <<= 1) {
        cross[0] += __shfl_xor(cross[0], s); cross[1] += __shfl_xor(cross[1], s);
        cross[2] += __shfl_xor(cross[2], s); cross[3] += __shfl_xor(cross[3], s);
    }
    if (la < 4) {
        const int grow = g * 16 + lb * 4 + la;
        float cv = (la == 0) ? cross[0] : (la == 1) ? cross[1] : (la == 2) ? cross[2] : cross[3];
        fCross[h * 32 + grow] = cv;
    }
    // ---- stage attn rows (bf16) [32][264]; this wave's col-half ----
    {
        const int rb = lb << 2;
#pragma unroll
        for (int nt = 0; nt < 8; ++nt) {
            const int cc = h * 128 + nt * 16 + la;
            sAttn[(g * 16 + rb + 0) * 264 + cc] = (unsigned short)bf16r(accL[nt][0]);
            sAttn[(g * 16 + rb + 1) * 264 + cc] = (unsigned short)bf16r(accL[nt][1]);
            sAttn[(g * 16 + rb + 2) * 264 + cc] = (unsigned short)bf16r(accL[nt][2]);
            sAttn[(g * 16 + rb + 3) * 264 + cc] = (unsigned short)bf16r(accL[nt][3]);
        }
    }
    __syncthreads();

    // ---- gv = attn @ G over this wave's 128 output cols (G symmetric, Gcm contiguous) ----
    ff4 accG[8];
#pragma unroll
    for (int i = 0; i < 8; ++i) accG[i] = (ff4)0.0f;
#pragma unroll
    for (int ks = 0; ks < 8; ++ks) {
        s8v aA = *(const s8v*)(sAttn + (g * 16 + la) * 264 + ks * 32 + lb * 8);
        const unsigned short* gp = gbase + (size_t)ks * 8192;
#pragma unroll
        for (int nt = 0; nt < 8; ++nt) {
            s8v bG = *(const s8v*)(gp + nt * 512);
            accG[nt] = __builtin_amdgcn_mfma_f32_16x16x32_bf16(aA, bG, accG[nt], 0, 0, 0);
        }
    }
    ff4 quad = (ff4)0.0f;
#pragma unroll
    for (int nt = 0; nt < 8; ++nt) {
        quad[0] = fmaf(accL[nt][0], accG[nt][0], quad[0]);
        quad[1] = fmaf(accL[nt][1], accG[nt][1], quad[1]);
        quad[2] = fmaf(accL[nt][2], accG[nt][2], quad[2]);
        quad[3] = fmaf(accL[nt][3], accG[nt][3], quad[3]);
    }
#pragma unroll
    for (int s = 1; s < 16; s <<= 1) {
        quad[0] += __shfl_xor(quad[0], s); quad[1] += __shfl_xor(quad[1], s);
        quad[2] += __shfl_xor(quad[2], s); quad[3] += __shfl_xor(quad[3], s);
    }
    if (la < 4) {
        const int grow = g * 16 + lb * 4 + la;
        float qv = (la == 0) ? quad[0] : (la == 1) ? quad[1] : (la == 2) ? quad[2] : quad[3];
        fQuad[h * 32 + grow] = qv;
    }
    __syncthreads();

    // ---- score & per-wave loss partial ----
    float val = 0.f;
    if (h == 0 && la < 4) {
        const int grow = g * 16 + lb * 4 + la;
        float s2 = fAux[grow] + 2.0f * (fCross[grow] + fCross[32 + grow])
                 + (fQuad[grow] + fQuad[32 + grow]);
        float sc = sqrtf(fmaxf(s2, 0.0f));
        const int gr = row0 + grow;
        val = (float)(2 * label[gr] - 1) * sc;
    }
#pragma unroll
    for (int s = 1; s < 64; s <<= 1) val += __shfl_xor(val, s);
    if (l == 0) partials[blockIdx.x * 4 + w] = val;
}

// ---- deterministic final reduction of per-wave partials -> loss ----
__global__ void finalize_kernel(const float* __restrict__ partials, float* __restrict__ out,
                                int np, float invB) {
    const int t = threadIdx.x;
    float v = 0.f;
    for (int i = t; i < np; i += 256) v += partials[i];
#pragma unroll
    for (int s = 1; s < 64; s <<= 1) v += __shfl_xor(v, s);
    __shared__ float ws4[4];
    if ((t & 63) == 0) ws4[t >> 6] = v;
    __syncthreads();
    if (t == 0) out[0] = (ws4[0] + ws4[1] + ws4[2] + ws4[3]) * invB;
}

extern "C" void kernel_launch(void* const* d_in, const int* in_sizes, int n_in,
                              void* d_out, int out_size, void* d_ws, size_t ws_size,
                              hipStream_t stream) {
    const float* user  = (const float*)d_in[0];
    const float* music = (const float*)d_in[1];
    const float* mem   = (const float*)d_in[2];
    const float* Wout  = (const float*)d_in[3];
    const float* bout  = (const float*)d_in[4];
    const int*   label = (const int*)d_in[5];
    const int Bn   = in_sizes[0] / Hd;   // 65536
    const int nblk = Bn / RB;            // 2048

    unsigned short* memB = (unsigned short*)d_ws;                                  // 512 KB
    unsigned short* Wbf  = (unsigned short*)((char*)d_ws + 524288);                // 4 KB
    unsigned short* Gcm  = (unsigned short*)((char*)d_ws + 524288 + 4096);         // 128 KB
    float* partials      = (float*)((char*)d_ws + 524288 + 4096 + 131072);         // 32 KB

    conv_mem_kernel<<<128, 256, 0, stream>>>(mem, memB);
    conv_w_kernel<<<1, 256, 0, stream>>>(Wout, Wbf);
    gram_kernel<<<64, 256, 0, stream>>>(mem, Gcm);
    fused_kernel<<<nblk, 256, 0, stream>>>(user, music, bout, label, memB, Wbf, Gcm,
                                           (float*)d_out, partials);
    finalize_kernel<<<1, 256, 0, stream>>>(partials, (float*)d_out, nblk * 4, 1.0f / (float)Bn);
}

// Round 9
// 307.739 us; speedup vs baseline: 1.2284x; 1.2284x over previous
//
#include <hip/hip_runtime.h>
#include <hip/hip_bf16.h>

typedef float ff4 __attribute__((ext_vector_type(4)));
typedef short s8v __attribute__((ext_vector_type(8)));
typedef unsigned int u4v __attribute__((ext_vector_type(4)));

#define Hd 1024
#define Nn 256
#define RB 32

__device__ __forceinline__ unsigned bf16r(float f) {
    unsigned u = __builtin_bit_cast(unsigned, f);
    return (u + 0x7FFFu + ((u >> 16) & 1u)) >> 16;   // RNE f32->bf16
}

__device__ __forceinline__ unsigned cvtpk(float lo, float hi) {
    unsigned r;
    asm("v_cvt_pk_bf16_f32 %0, %1, %2" : "=v"(r) : "v"(lo), "v"(hi));
    return r;
}

__device__ __forceinline__ void glds16(void* lds, const void* g) {
    __builtin_amdgcn_global_load_lds(
        (const __attribute__((address_space(1))) unsigned int*)g,
        (__attribute__((address_space(3))) unsigned int*)lds, 16, 0, 0);
}

// ---- memB: chunk-major KC=32, 16B-block swizzled (verified R5/R7):
// byte(c,r,b) at c*16384 + r*64 + ((b ^ ((r>>1)&3))*16) = bf16(mem[r][c*32 + b*8 .. +8])
__global__ void conv_mem_kernel(const float* __restrict__ mem, unsigned short* __restrict__ memB) {
    int g = blockIdx.x * 256 + threadIdx.x;   // 0..32767
    int b = g & 3;
    int r = (g >> 2) & 255;
    int c = g >> 10;
    const float* src = mem + (size_t)r * Hd + c * 32 + b * 8;
    ff4 a0 = *(const ff4*)src;
    ff4 a1 = *(const ff4*)(src + 4);
    u4v v;
    v[0] = bf16r(a0[0]) | (bf16r(a0[1]) << 16);
    v[1] = bf16r(a0[2]) | (bf16r(a0[3]) << 16);
    v[2] = bf16r(a1[0]) | (bf16r(a1[1]) << 16);
    v[3] = bf16r(a1[2]) | (bf16r(a1[3]) << 16);
    size_t dst = (size_t)c * 16384 + (size_t)r * 64 + (size_t)((b ^ ((r >> 1) & 3)) * 16);
    *(u4v*)((char*)memB + dst) = v;
}

// ---- Wbf[c][h] = bf16(Wout[h][c]), c in {0,1} ----
__global__ void conv_w_kernel(const float* __restrict__ Wout, unsigned short* __restrict__ Wbf) {
    int t = threadIdx.x;
    int c = t >> 7;
    int h0 = (t & 127) * 8;
    u4v v;
#pragma unroll
    for (int j = 0; j < 4; ++j) {
        unsigned lo = bf16r(Wout[(h0 + 2 * j) * 2 + c]);
        unsigned hi = bf16r(Wout[(h0 + 2 * j + 1) * 2 + c]);
        v[j] = lo | (hi << 16);
    }
    *(u4v*)(Wbf + (size_t)c * Hd + h0) = v;
}

// ---- Gram G = mem @ mem^T, chunk-major: Gcm[(gj>>5)*8192 + gi*32 + (gj&31)] (verified R8) ----
__global__ __launch_bounds__(256) void gram_kernel(const float* __restrict__ mem,
                                                   unsigned short* __restrict__ Gcm) {
    __shared__ float LA[32][132];
    __shared__ float LB[32][132];
    const int t = threadIdx.x;
    const int bi = blockIdx.x >> 3, bj = blockIdx.x & 7;
    const int j = t & 31, i0 = t >> 5;
    float acc0 = 0.f, acc1 = 0.f, acc2 = 0.f, acc3 = 0.f;
    for (int kc = 0; kc < Hd; kc += 128) {
        __syncthreads();
#pragma unroll
        for (int q = 0; q < 4; ++q) {
            int c = t + q * 256;
            int r = c >> 5, fc = (c & 31) << 2;
            *(ff4*)&LA[r][fc] = *(const ff4*)(mem + (size_t)(bi * 32 + r) * Hd + kc + fc);
            *(ff4*)&LB[r][fc] = *(const ff4*)(mem + (size_t)(bj * 32 + r) * Hd + kc + fc);
        }
        __syncthreads();
#pragma unroll 4
        for (int kk = 0; kk < 128; kk += 4) {
            ff4 b = *(const ff4*)&LB[j][kk];
            ff4 a0 = *(const ff4*)&LA[i0][kk];
            ff4 a1 = *(const ff4*)&LA[i0 + 8][kk];
            ff4 a2 = *(const ff4*)&LA[i0 + 16][kk];
            ff4 a3 = *(const ff4*)&LA[i0 + 24][kk];
            acc0 += a0[0]*b[0] + a0[1]*b[1] + a0[2]*b[2] + a0[3]*b[3];
            acc1 += a1[0]*b[0] + a1[1]*b[1] + a1[2]*b[2] + a1[3]*b[3];
            acc2 += a2[0]*b[0] + a2[1]*b[1] + a2[2]*b[2] + a2[3]*b[3];
            acc3 += a3[0]*b[0] + a3[1]*b[1] + a3[2]*b[2] + a3[3]*b[3];
        }
    }
    const size_t base = (size_t)bj * 8192 + (size_t)j;
    Gcm[base + (size_t)(bi * 32 + i0 +  0) * 32] = (unsigned short)bf16r(acc0);
    Gcm[base + (size_t)(bi * 32 + i0 +  8) * 32] = (unsigned short)bf16r(acc1);
    Gcm[base + (size_t)(bi * 32 + i0 + 16) * 32] = (unsigned short)bf16r(acc2);
    Gcm[base + (size_t)(bi * 32 + i0 + 24) * 32] = (unsigned short)bf16r(acc3);
}

struct UM { ff4 u0, u1, m0, m1; };

// ---- fused main kernel: 32 rows/block, 4 waves (2 row-groups x 2 N-halves),
//      WAVE-PRIVATE double-buffered glds pipeline, ZERO barriers in main loop ----
__global__ __launch_bounds__(256, 2) void fused_kernel(
    const float* __restrict__ user, const float* __restrict__ music,
    const float* __restrict__ bout, const int* __restrict__ label,
    const unsigned short* __restrict__ memB,   // [32][256][32] bf16, block-swizzled
    const unsigned short* __restrict__ Wbf,    // [2][1024] bf16
    const unsigned short* __restrict__ Gcm,    // [8][256][32] bf16 chunk-major
    float* __restrict__ out, float* __restrict__ partials)
{
    __shared__ __align__(16) unsigned char smem[65536];   // 4 waves x 2 x 8KB private bufs
    __shared__ float fMax[64], fSum[64], fCross[64], fQuad[64], fAux[32];
    unsigned short* sAttn = (unsigned short*)smem;        // epilogue alias [32][264]

    const int t = threadIdx.x;
    const int w = t >> 6;
    const int l = t & 63;
    const int la = l & 15, lb = l >> 4;
    const int g = w >> 1;        // row-group (16 rows)
    const int h = w & 1;         // N-half (128 cols)
    const int row0 = blockIdx.x * RB;
    const int myrow = row0 + g * 16 + la;

    const float* uR = user  + (size_t)myrow * Hd + lb * 8;
    const float* mR = music + (size_t)myrow * Hd + lb * 8;
    unsigned char* bufb = smem + w * 16384;                      // this wave's 2 bufs
    const char* gsrcW = (const char*)memB + h * 8192 + l * 16;   // + c*16384
    const unsigned short* wrowB = Wbf + (size_t)(la < 2 ? la : 1) * Hd + lb * 8;
    const unsigned short* gbase = Gcm + h * 4096 + la * 32 + lb * 8;
    const int roff = la * 64 + ((lb ^ ((la >> 1) & 3)) << 4);

    ff4 accL[8], accD[8];
#pragma unroll
    for (int i = 0; i < 8; ++i) { accL[i] = (ff4)0.0f; accD[i] = (ff4)0.0f; }
    ff4 accH = (ff4)0.0f;
    float sd2 = 0.f;

    UM A0, A1, B0, B1;

#define LOADUM(D, K) {                                                          \
        const float* _up = uR + (K) * 32;                                       \
        const float* _mp = mR + (K) * 32;                                       \
        D.u0 = *(const ff4*)_up; D.u1 = *(const ff4*)(_up + 4);                 \
        D.m0 = *(const ff4*)_mp; D.m1 = *(const ff4*)(_mp + 4); }

#define CVT(S, FS, FD) {                                                        \
        float s0=S.u0[0]*S.m0[0], s1=S.u0[1]*S.m0[1], s2=S.u0[2]*S.m0[2], s3=S.u0[3]*S.m0[3]; \
        float s4=S.u1[0]*S.m1[0], s5=S.u1[1]*S.m1[1], s6=S.u1[2]*S.m1[2], s7=S.u1[3]*S.m1[3]; \
        float d0=S.u0[0]-S.m0[0], d1=S.u0[1]-S.m0[1], d2=S.u0[2]-S.m0[2], d3=S.u0[3]-S.m0[3]; \
        float d4=S.u1[0]-S.m1[0], d5=S.u1[1]-S.m1[1], d6=S.u1[2]-S.m1[2], d7=S.u1[3]-S.m1[3]; \
        sd2=fmaf(d0,d0,sd2); sd2=fmaf(d1,d1,sd2); sd2=fmaf(d2,d2,sd2); sd2=fmaf(d3,d3,sd2);   \
        sd2=fmaf(d4,d4,sd2); sd2=fmaf(d5,d5,sd2); sd2=fmaf(d6,d6,sd2); sd2=fmaf(d7,d7,sd2);   \
        u4v ps, pd;                                                             \
        ps[0]=cvtpk(s0,s1); ps[1]=cvtpk(s2,s3); ps[2]=cvtpk(s4,s5); ps[3]=cvtpk(s6,s7);       \
        pd[0]=cvtpk(d0,d1); pd[1]=cvtpk(d2,d3); pd[2]=cvtpk(d4,d5); pd[3]=cvtpk(d6,d7);       \
        FS = __builtin_bit_cast(s8v, ps);                                       \
        FD = __builtin_bit_cast(s8v, pd); }

    // ---- prologue: bW(0), glds(0), um(0), um(1) ----
    s8v bW = *(const s8v*)(wrowB);
#pragma unroll
    for (int i = 0; i < 8; ++i)
        glds16(bufb + i * 1024, gsrcW + i * 1024);
    LOADUM(A0, 0)
    LOADUM(A1, 1)
    __builtin_amdgcn_sched_barrier(0);

    // Per body: issues-after-glds(c) = um(8, every other body) + bW(1) + glds(c+1)(8) = 17,
    // uniform across parity and (via wrap dummies) across the tail -> vmcnt(17) == glds(c) done.
#define BODY(C, CS, DOISS, I0, I1)                                              \
    {                                                                           \
        const int cn = ((C) + 1) & 31;                                          \
        s8v bWn = *(const s8v*)(wrowB + cn * 32);                               \
        const char* gs = gsrcW + (size_t)cn * 16384;                            \
        unsigned char* db = bufb + (((C) + 1) & 1) * 8192;                      \
        _Pragma("unroll")                                                       \
        for (int i = 0; i < 8; ++i) glds16(db + i * 1024, gs + i * 1024);       \
        if (DOISS) { LOADUM(I0, ((C) + 2) & 31) LOADUM(I1, ((C) + 3) & 31) }    \
        __builtin_amdgcn_sched_barrier(0);                                      \
        s8v fs, fd;                                                             \
        CVT(CS, fs, fd)                                                         \
        asm volatile("s_waitcnt vmcnt(17)" ::: "memory");                       \
        __builtin_amdgcn_sched_barrier(0);                                      \
        const unsigned char* mb = bufb + ((C) & 1) * 8192;                      \
        _Pragma("unroll")                                                       \
        for (int nt = 0; nt < 8; ++nt) {                                        \
            s8v bM = *(const s8v*)(mb + nt * 1024 + roff);                      \
            accL[nt] = __builtin_amdgcn_mfma_f32_16x16x32_bf16(fs, bM, accL[nt], 0, 0, 0); \
            accD[nt] = __builtin_amdgcn_mfma_f32_16x16x32_bf16(fd, bM, accD[nt], 0, 0, 0); \
        }                                                                       \
        accH = __builtin_amdgcn_mfma_f32_16x16x32_bf16(fs, bW, accH, 0, 0, 0);  \
        bW = bWn;                                                               \
        __builtin_amdgcn_sched_barrier(0);                                      \
    }

    for (int c = 0; c < 32; c += 4) {
        BODY(c + 0, A0, 1, B0, B1)
        BODY(c + 1, A1, 0, B0, B1)
        BODY(c + 2, B0, 1, A0, A1)
        BODY(c + 3, B1, 0, A0, A1)
    }
#undef BODY
#undef CVT
#undef LOADUM

    // drain wrap prefetches, then the only workgroup sync before the epilogue alias
    asm volatile("s_waitcnt vmcnt(0)" ::: "memory");
    __syncthreads();

    // ---- classification head (cols 0,1 live in lanes la<2; h==0 waves store) ----
    if (h == 0 && la < 2) {
#pragma unroll
        for (int j = 0; j < 4; ++j) {
            int gr = row0 + g * 16 + lb * 4 + j;
            out[1 + gr * 2 + la] = accH[j] + bout[la];
        }
    }
    // ---- ||d||^2 per row: reduce over 4 lb col-groups; h==0 writes ----
    sd2 += __shfl_xor(sd2, 16);
    sd2 += __shfl_xor(sd2, 32);
    if (h == 0 && lb == 0) fAux[g * 16 + la] = sd2;

    // ---- half-softmax: local max & sumexp over this wave's 128 cols ----
    ff4 mx = accL[0];
#pragma unroll
    for (int nt = 1; nt < 8; ++nt) {
        mx[0] = fmaxf(mx[0], accL[nt][0]); mx[1] = fmaxf(mx[1], accL[nt][1]);
        mx[2] = fmaxf(mx[2], accL[nt][2]); mx[3] = fmaxf(mx[3], accL[nt][3]);
    }
#pragma unroll
    for (int s = 1; s < 16; s <<= 1) {
        mx[0] = fmaxf(mx[0], __shfl_xor(mx[0], s));
        mx[1] = fmaxf(mx[1], __shfl_xor(mx[1], s));
        mx[2] = fmaxf(mx[2], __shfl_xor(mx[2], s));
        mx[3] = fmaxf(mx[3], __shfl_xor(mx[3], s));
    }
    ff4 sm = (ff4)0.0f;
#pragma unroll
    for (int nt = 0; nt < 8; ++nt) {
        sm[0] += __expf(accL[nt][0] - mx[0]); sm[1] += __expf(accL[nt][1] - mx[1]);
        sm[2] += __expf(accL[nt][2] - mx[2]); sm[3] += __expf(accL[nt][3] - mx[3]);
    }
#pragma unroll
    for (int s = 1; s < 16; s <<= 1) {
        sm[0] += __shfl_xor(sm[0], s); sm[1] += __shfl_xor(sm[1], s);
        sm[2] += __shfl_xor(sm[2], s); sm[3] += __shfl_xor(sm[3], s);
    }
    if (la < 4) {
        const int grow = g * 16 + lb * 4 + la;
        float mv = (la == 0) ? mx[0] : (la == 1) ? mx[1] : (la == 2) ? mx[2] : mx[3];
        float sv = (la == 0) ? sm[0] : (la == 1) ? sm[1] : (la == 2) ? sm[2] : sm[3];
        fMax[h * 32 + grow] = mv;
        fSum[h * 32 + grow] = sv;
    }
    __syncthreads();

    // ---- combine halves -> per-row M, 1/denom ----
    ff4 Mr, Dinv;
#pragma unroll
    for (int j = 0; j < 4; ++j) {
        const int grow = g * 16 + lb * 4 + j;
        float m0 = fMax[grow], m1 = fMax[32 + grow];
        float M = fmaxf(m0, m1);
        float den = fSum[grow] * __expf(m0 - M) + fSum[32 + grow] * __expf(m1 - M);
        Mr[j] = M; Dinv[j] = 1.0f / den;
    }
    // ---- attn + cross partial ----
    ff4 cross = (ff4)0.0f;
#pragma unroll
    for (int nt = 0; nt < 8; ++nt) {
        accL[nt][0] = __expf(accL[nt][0] - Mr[0]) * Dinv[0];
        accL[nt][1] = __expf(accL[nt][1] - Mr[1]) * Dinv[1];
        accL[nt][2] = __expf(accL[nt][2] - Mr[2]) * Dinv[2];
        accL[nt][3] = __expf(accL[nt][3] - Mr[3]) * Dinv[3];
        cross[0] = fmaf(accL[nt][0], accD[nt][0], cross[0]);
        cross[1] = fmaf(accL[nt][1], accD[nt][1], cross[1]);
        cross[2] = fmaf(accL[nt][2], accD[nt][2], cross[2]);
        cross[3] = fmaf(accL[nt][3], accD[nt][3], cross[3]);
    }
#pragma unroll
    for (int s = 1; s < 16; s <<= 1) {
        cross[0] += __shfl_xor(cross[0], s); cross[1] += __shfl_xor(cross[1], s);
        cross[2] += __shfl_xor(cross[2], s); cross[3] += __shfl_xor(cross[3], s);
    }
    if (la < 4) {
        const int grow = g * 16 + lb * 4 + la;
        float cv = (la == 0) ? cross[0] : (la == 1) ? cross[1] : (la == 2) ? cross[2] : cross[3];
        fCross[h * 32 + grow] = cv;
    }
    // ---- stage attn rows (bf16) [32][264]; this wave's col-half ----
    {
        const int rb = lb << 2;
#pragma unroll
        for (int nt = 0; nt < 8; ++nt) {
            const int cc = h * 128 + nt * 16 + la;
            sAttn[(g * 16 + rb + 0) * 264 + cc] = (unsigned short)bf16r(accL[nt][0]);
            sAttn[(g * 16 + rb + 1) * 264 + cc] = (unsigned short)bf16r(accL[nt][1]);
            sAttn[(g * 16 + rb + 2) * 264 + cc] = (unsigned short)bf16r(accL[nt][2]);
            sAttn[(g * 16 + rb + 3) * 264 + cc] = (unsigned short)bf16r(accL[nt][3]);
        }
    }
    __syncthreads();

    // ---- gv = attn @ G over this wave's 128 output cols (G symmetric, Gcm contiguous) ----
    ff4 accG[8];
#pragma unroll
    for (int i = 0; i < 8; ++i) accG[i] = (ff4)0.0f;
#pragma unroll
    for (int ks = 0; ks < 8; ++ks) {
        s8v aA = *(const s8v*)(sAttn + (g * 16 + la) * 264 + ks * 32 + lb * 8);
        const unsigned short* gp = gbase + (size_t)ks * 8192;
#pragma unroll
        for (int nt = 0; nt < 8; ++nt) {
            s8v bG = *(const s8v*)(gp + nt * 512);
            accG[nt] = __builtin_amdgcn_mfma_f32_16x16x32_bf16(aA, bG, accG[nt], 0, 0, 0);
        }
    }
    ff4 quad = (ff4)0.0f;
#pragma unroll
    for (int nt = 0; nt < 8; ++nt) {
        quad[0] = fmaf(accL[nt][0], accG[nt][0], quad[0]);
        quad[1] = fmaf(accL[nt][1], accG[nt][1], quad[1]);
        quad[2] = fmaf(accL[nt][2], accG[nt][2], quad[2]);
        quad[3] = fmaf(accL[nt][3], accG[nt][3], quad[3]);
    }
#pragma unroll
    for (int s = 1; s < 16; s <<= 1) {
        quad[0] += __shfl_xor(quad[0], s); quad[1] += __shfl_xor(quad[1], s);
        quad[2] += __shfl_xor(quad[2], s); quad[3] += __shfl_xor(quad[3], s);
    }
    if (la < 4) {
        const int grow = g * 16 + lb * 4 + la;
        float qv = (la == 0) ? quad[0] : (la == 1) ? quad[1] : (la == 2) ? quad[2] : quad[3];
        fQuad[h * 32 + grow] = qv;
    }
    __syncthreads();

    // ---- score & per-wave loss partial ----
    float val = 0.f;
    if (h == 0 && la < 4) {
        const int grow = g * 16 + lb * 4 + la;
        float s2 = fAux[grow] + 2.0f * (fCross[grow] + fCross[32 + grow])
                 + (fQuad[grow] + fQuad[32 + grow]);
        float sc = sqrtf(fmaxf(s2, 0.0f));
        const int gr = row0 + grow;
        val = (float)(2 * label[gr] - 1) * sc;
    }
#pragma unroll
    for (int s = 1; s < 64; s <<= 1) val += __shfl_xor(val, s);
    if (l == 0) partials[blockIdx.x * 4 + w] = val;
}

// ---- deterministic final reduction of per-wave partials -> loss ----
__global__ void finalize_kernel(const float* __restrict__ partials, float* __restrict__ out,
                                int np, float invB) {
    const int t = threadIdx.x;
    float v = 0.f;
    for (int i = t; i < np; i += 256) v += partials[i];
#pragma unroll
    for (int s = 1; s < 64; s <<= 1) v += __shfl_xor(v, s);
    __shared__ float ws4[4];
    if ((t & 63) == 0) ws4[t >> 6] = v;
    __syncthreads();
    if (t == 0) out[0] = (ws4[0] + ws4[1] + ws4[2] + ws4[3]) * invB;
}

extern "C" void kernel_launch(void* const* d_in, const int* in_sizes, int n_in,
                              void* d_out, int out_size, void* d_ws, size_t ws_size,
                              hipStream_t stream) {
    const float* user  = (const float*)d_in[0];
    const float* music = (const float*)d_in[1];
    const float* mem   = (const float*)d_in[2];
    const float* Wout  = (const float*)d_in[3];
    const float* bout  = (const float*)d_in[4];
    const int*   label = (const int*)d_in[5];
    const int Bn   = in_sizes[0] / Hd;   // 65536
    const int nblk = Bn / RB;            // 2048

    unsigned short* memB = (unsigned short*)d_ws;                                  // 512 KB
    unsigned short* Wbf  = (unsigned short*)((char*)d_ws + 524288);                // 4 KB
    unsigned short* Gcm  = (unsigned short*)((char*)d_ws + 524288 + 4096);         // 128 KB
    float* partials      = (float*)((char*)d_ws + 524288 + 4096 + 131072);         // 32 KB

    conv_mem_kernel<<<128, 256, 0, stream>>>(mem, memB);
    conv_w_kernel<<<1, 256, 0, stream>>>(Wout, Wbf);
    gram_kernel<<<64, 256, 0, stream>>>(mem, Gcm);
    fused_kernel<<<nblk, 256, 0, stream>>>(user, music, bout, label, memB, Wbf, Gcm,
                                           (float*)d_out, partials);
    finalize_kernel<<<1, 256, 0, stream>>>(partials, (float*)d_out, nblk * 4, 1.0f / (float)Bn);
}